// Round 4
// baseline (139.757 us; speedup 1.0000x reference)
//
#include <hip/hip_runtime.h>
#include <math.h>

#define L_SEQ 2048
#define DM    256
#define NH    8
#define HD    32

typedef __attribute__((ext_vector_type(8))) short bf16x8;
typedef __attribute__((ext_vector_type(8))) unsigned short u16x8;
typedef __attribute__((ext_vector_type(4))) float f32x4;

__device__ __forceinline__ unsigned short f2bf(float f) {
    unsigned int u = __builtin_bit_cast(unsigned int, f);
    u += 0x7fff + ((u >> 16) & 1);          // RNE (finite values only)
    return (unsigned short)(u >> 16);
}

// ---------------------------------------------------------------------------
// Kernel 0: prep.
//  blocks [0,384):  fp32 -> bf16 cvt of x, Wq, Wk, Wv, Wo (8 elems/thread)
//  blocks [384,400): bias-MLP lookup table T[4096] over dist in [0,16]
//                    T[n] = beta * clamp(mlp(n/256), -10, 0), fp32.
// ---------------------------------------------------------------------------
__global__ __launch_bounds__(256) void prep(
    const float* __restrict__ x,  const float* __restrict__ wq,
    const float* __restrict__ wk, const float* __restrict__ wv,
    const float* __restrict__ wo,
    const float* __restrict__ k_w1, const float* __restrict__ k_b1,
    const float* __restrict__ k_w2, const float* __restrict__ k_b2,
    const float* __restrict__ beta_p,
    unsigned short* __restrict__ xb,  unsigned short* __restrict__ wqb,
    unsigned short* __restrict__ wkb, unsigned short* __restrict__ wvb,
    unsigned short* __restrict__ wob, float* __restrict__ T)
{
    const int bx = blockIdx.x, t = threadIdx.x;
    if (bx < 384) {
        int e = (bx * 256 + t) * 8;   // 786432 total elems
        const float* src; unsigned short* dst; int off;
        if      (e < 524288) { src = x;  dst = xb;  off = e; }
        else if (e < 589824) { src = wq; dst = wqb; off = e - 524288; }
        else if (e < 655360) { src = wk; dst = wkb; off = e - 589824; }
        else if (e < 720896) { src = wv; dst = wvb; off = e - 655360; }
        else                 { src = wo; dst = wob; off = e - 720896; }
        float4 u = *(const float4*)(src + off);
        float4 v = *(const float4*)(src + off + 4);
        ushort4 a, b;
        a.x = f2bf(u.x); a.y = f2bf(u.y); a.z = f2bf(u.z); a.w = f2bf(u.w);
        b.x = f2bf(v.x); b.y = f2bf(v.y); b.z = f2bf(v.z); b.w = f2bf(v.w);
        *(ushort4*)(dst + off)     = a;
        *(ushort4*)(dst + off + 4) = b;
    } else {
        int n = (bx - 384) * 256 + t;            // 0..4095
        float d = (float)n * (1.0f / 256.0f);
        float s = 0.f;
#pragma unroll
        for (int k = 0; k < 32; ++k)
            s += fmaxf(fmaf(d, k_w1[k], k_b1[k]), 0.f) * k_w2[k];
        s = fminf(fmaxf(s + k_b2[0], -10.f), 0.f);
        T[n] = beta_p[0] * s;
    }
}

// ---------------------------------------------------------------------------
// Kernel 1: fused front end.
//   blocks [0,384):  QKV projection via MFMA on bf16 inputs.
//                    z = bx>>7 selects Q/K/V; V written TRANSPOSED (Vt[d][key'])
//                    with the permuted key layout (pos = 2*(loc&15)+(loc>>4)).
//   blocks [384,2432): geometric bias via table lerp -> biasP bf16,
//                    same key permutation. One block per bias row; thread t
//                    covers cols 8t..8t+7 with a single 16 B store.
// ---------------------------------------------------------------------------
__global__ __launch_bounds__(256) void fused_front(
    const unsigned short* __restrict__ xb, const float* __restrict__ pts,
    const unsigned short* __restrict__ wqb, const float* __restrict__ bq,
    const unsigned short* __restrict__ wkb, const float* __restrict__ bk,
    const unsigned short* __restrict__ wvb, const float* __restrict__ bv,
    const float* __restrict__ T,
    unsigned short* __restrict__ Qb, unsigned short* __restrict__ Kb,
    unsigned short* __restrict__ Vt, unsigned short* __restrict__ biasP)
{
    const int bx = blockIdx.x;
    const int t = threadIdx.x;

    if (bx < 384) {
        const int z  = bx >> 7;
        const int r0 = (bx & 127) << 4;
        const int w = t >> 6, lane = t & 63, quad = lane >> 4, c = lane & 15;
        const int c0 = w * 64;
        const unsigned short* Wm = (z == 0) ? wqb : (z == 1) ? wkb : wvb;
        const float* bia         = (z == 0) ? bq  : (z == 1) ? bk  : bv;

        f32x4 acc[4] = {};
        for (int kt = 0; kt < 8; ++kt) {
            bf16x8 a = *(const bf16x8*)(xb + (size_t)(r0 + c) * DM + kt * 32 + quad * 8);
#pragma unroll
            for (int ct = 0; ct < 4; ++ct) {
                bf16x8 b = *(const bf16x8*)(Wm + (size_t)(c0 + ct * 16 + c) * DM + kt * 32 + quad * 8);
                acc[ct] = __builtin_amdgcn_mfma_f32_16x16x32_bf16(a, b, acc[ct], 0, 0, 0);
            }
        }
        if (z < 2) {
            unsigned short* out = (z == 0) ? Qb : Kb;
#pragma unroll
            for (int ct = 0; ct < 4; ++ct) {
                float bc = bia[c0 + ct * 16 + c];
#pragma unroll
                for (int reg = 0; reg < 4; ++reg) {
                    int r = r0 + quad * 4 + reg;
                    out[(size_t)r * DM + c0 + ct * 16 + c] = f2bf(acc[ct][reg] + bc);
                }
            }
        } else {
            // V: write transposed with key permutation. Vt[col][pos], col = h*32+d.
#pragma unroll
            for (int ct = 0; ct < 4; ++ct) {
                int col = c0 + ct * 16 + c;
                float bc = bia[col];
#pragma unroll
                for (int reg = 0; reg < 4; ++reg) {
                    int key = r0 + quad * 4 + reg;
                    int loc = key & 31;
                    int pos = (key & ~31) + 2 * (loc & 15) + (loc >> 4);
                    Vt[(size_t)col * L_SEQ + pos] = f2bf(acc[ct][reg] + bc);
                }
            }
        }
    } else {
        const int i = bx - 384;                  // bias row (query index)
        const int p0 = t * 8;                    // 8 permuted cols per thread
        const float xi = pts[i * 3], yi = pts[i * 3 + 1], zi = pts[i * 3 + 2];

        u16x8 o;
#pragma unroll
        for (int v = 0; v < 8; ++v) {
            int p = p0 + v, loc = p & 31, base = p & ~31;
            int k = base + (loc >> 1) + 16 * (loc & 1);
            float dx = xi - pts[k * 3], dy = yi - pts[k * 3 + 1], dz = zi - pts[k * 3 + 2];
            float dist = sqrtf(dx * dx + dy * dy + dz * dz);
            float fn = dist * 256.0f;
            int n = (int)fn; n = (n > 4094) ? 4094 : n;
            float fr = fn - (float)n;
            float t0 = T[n], t1 = T[n + 1];
            o[v] = f2bf(fmaf(fr, t1 - t0, t0));
        }
        *(u16x8*)(biasP + (size_t)i * L_SEQ + p0) = o;
    }
}

// ---------------------------------------------------------------------------
// Kernel 2: MFMA flash attention. Block = (32 q-rows, 1 head), 4 waves with
// 4-way key split (512 keys each). Fixed-shift softmax (M=10) -> partials
// combine by plain sums. No __syncthreads in the K-loop; P does a wave-local
// LDS transpose (C-layout -> A-layout) in the permuted key order.
// Grid dim3(64,8): linear id = x + 64*y, XCD round-robin puts all 8 heads of
// q-blocks with x%8==const on one XCD -> biasP row-slices are L2-hits across
// heads (measured best layout; head-per-XCD swizzle was 0 to -0.7us).
// ---------------------------------------------------------------------------
__global__ __launch_bounds__(256) void attn_mfma(
    const unsigned short* __restrict__ Qb, const unsigned short* __restrict__ Kb,
    const unsigned short* __restrict__ Vt, const unsigned short* __restrict__ biasP,
    unsigned short* __restrict__ Ab)
{
    __shared__ unsigned short Plds[4][32][40];
    __shared__ float Ol[4][32][36];
    __shared__ float Ll[4][32];
    const int t = threadIdx.x, w = t >> 6, lane = t & 63, quad = lane >> 4, c = lane & 15;
    const int h = blockIdx.y, r0 = blockIdx.x * 32;
    const int kbase = w * 512;
    const f32x4 Z = {};

    bf16x8 qf0 = *(const bf16x8*)(Qb + (size_t)(r0 + c) * DM + h * HD + quad * 8);
    bf16x8 qf1 = *(const bf16x8*)(Qb + (size_t)(r0 + 16 + c) * DM + h * HD + quad * 8);

    f32x4 O00 = {}, O01 = {}, O10 = {}, O11 = {};
    float l0[4] = {0.f,0.f,0.f,0.f}, l1[4] = {0.f,0.f,0.f,0.f};

    const float LOG2E = 1.4426950408889634f;
    const float C1 = 0.17677669529663687f * LOG2E;  // SCALE * log2e
    const float MC = -10.0f * LOG2E;                // fixed shift

    const unsigned short* Kp  = Kb + (size_t)h * HD + quad * 8;
    const unsigned short* Vp0 = Vt + (size_t)(h * HD + c) * L_SEQ + quad * 8;
    const unsigned short* Vp1 = Vt + (size_t)(h * HD + 16 + c) * L_SEQ + quad * 8;
    const int br0 = r0 + quad * 4;

    bf16x8 kf0 = *(const bf16x8*)(Kp + (size_t)(kbase + c) * DM);
    bf16x8 kf1 = *(const bf16x8*)(Kp + (size_t)(kbase + 16 + c) * DM);
    bf16x8 vf0 = *(const bf16x8*)(Vp0 + kbase);
    bf16x8 vf1 = *(const bf16x8*)(Vp1 + kbase);
    unsigned int bu0[4], bu1[4];
#pragma unroll
    for (int reg = 0; reg < 4; ++reg) {
        bu0[reg] = *(const unsigned int*)(biasP + (size_t)(br0 + reg) * L_SEQ + kbase + c * 2);
        bu1[reg] = *(const unsigned int*)(biasP + (size_t)(br0 + 16 + reg) * L_SEQ + kbase + c * 2);
    }

    for (int kt = 0; kt < 16; ++kt) {
        const int kn = kbase + (kt + 1) * 32;
        bf16x8 nk0 = kf0, nk1 = kf1, nv0 = vf0, nv1 = vf1;
        unsigned int nbu0[4], nbu1[4];
#pragma unroll
        for (int reg = 0; reg < 4; ++reg) { nbu0[reg] = bu0[reg]; nbu1[reg] = bu1[reg]; }
        if (kt < 15) {   // prefetch next tile's fragments (no barrier in this loop)
            nk0 = *(const bf16x8*)(Kp + (size_t)(kn + c) * DM);
            nk1 = *(const bf16x8*)(Kp + (size_t)(kn + 16 + c) * DM);
            nv0 = *(const bf16x8*)(Vp0 + kn);
            nv1 = *(const bf16x8*)(Vp1 + kn);
#pragma unroll
            for (int reg = 0; reg < 4; ++reg) {
                nbu0[reg] = *(const unsigned int*)(biasP + (size_t)(br0 + reg) * L_SEQ + kn + c * 2);
                nbu1[reg] = *(const unsigned int*)(biasP + (size_t)(br0 + 16 + reg) * L_SEQ + kn + c * 2);
            }
        }

        f32x4 S00 = __builtin_amdgcn_mfma_f32_16x16x32_bf16(qf0, kf0, Z, 0, 0, 0);
        f32x4 S01 = __builtin_amdgcn_mfma_f32_16x16x32_bf16(qf0, kf1, Z, 0, 0, 0);
        f32x4 S10 = __builtin_amdgcn_mfma_f32_16x16x32_bf16(qf1, kf0, Z, 0, 0, 0);
        f32x4 S11 = __builtin_amdgcn_mfma_f32_16x16x32_bf16(qf1, kf1, Z, 0, 0, 0);

#pragma unroll
        for (int reg = 0; reg < 4; ++reg) {
            unsigned int u = bu0[reg];
            float blo = __builtin_bit_cast(float, u << 16);
            float bhi = __builtin_bit_cast(float, u & 0xffff0000u);
            float p0 = __builtin_exp2f(fmaf(S00[reg], C1, fmaf(blo, LOG2E, MC)));
            float p1 = __builtin_exp2f(fmaf(S01[reg], C1, fmaf(bhi, LOG2E, MC)));
            l0[reg] += p0 + p1;
            unsigned int pb = __builtin_amdgcn_perm(
                __builtin_bit_cast(unsigned int, p1),
                __builtin_bit_cast(unsigned int, p0), 0x07060302);
            *(unsigned int*)&Plds[w][quad * 4 + reg][c * 2] = pb;

            u = bu1[reg];
            blo = __builtin_bit_cast(float, u << 16);
            bhi = __builtin_bit_cast(float, u & 0xffff0000u);
            p0 = __builtin_exp2f(fmaf(S10[reg], C1, fmaf(blo, LOG2E, MC)));
            p1 = __builtin_exp2f(fmaf(S11[reg], C1, fmaf(bhi, LOG2E, MC)));
            l1[reg] += p0 + p1;
            pb = __builtin_amdgcn_perm(
                __builtin_bit_cast(unsigned int, p1),
                __builtin_bit_cast(unsigned int, p0), 0x07060302);
            *(unsigned int*)&Plds[w][16 + quad * 4 + reg][c * 2] = pb;
        }

        bf16x8 pa0 = *(const bf16x8*)&Plds[w][c][quad * 8];
        bf16x8 pa1 = *(const bf16x8*)&Plds[w][16 + c][quad * 8];
        O00 = __builtin_amdgcn_mfma_f32_16x16x32_bf16(pa0, vf0, O00, 0, 0, 0);
        O01 = __builtin_amdgcn_mfma_f32_16x16x32_bf16(pa0, vf1, O01, 0, 0, 0);
        O10 = __builtin_amdgcn_mfma_f32_16x16x32_bf16(pa1, vf0, O10, 0, 0, 0);
        O11 = __builtin_amdgcn_mfma_f32_16x16x32_bf16(pa1, vf1, O11, 0, 0, 0);

        kf0 = nk0; kf1 = nk1; vf0 = nv0; vf1 = nv1;
#pragma unroll
        for (int reg = 0; reg < 4; ++reg) { bu0[reg] = nbu0[reg]; bu1[reg] = nbu1[reg]; }
    }

    // reduce l across the 16 lanes of each quad (rows live per (quad,reg))
#pragma unroll
    for (int off = 1; off < 16; off <<= 1) {
#pragma unroll
        for (int reg = 0; reg < 4; ++reg) {
            l0[reg] += __shfl_xor(l0[reg], off, 16);
            l1[reg] += __shfl_xor(l1[reg], off, 16);
        }
    }
    // dump per-wave partials (plain sums thanks to fixed shift)
#pragma unroll
    for (int reg = 0; reg < 4; ++reg) {
        int row = quad * 4 + reg;
        Ol[w][row][c]           = O00[reg];
        Ol[w][row][16 + c]      = O01[reg];
        Ol[w][row + 16][c]      = O10[reg];
        Ol[w][row + 16][16 + c] = O11[reg];
    }
    if (c == 0) {
#pragma unroll
        for (int reg = 0; reg < 4; ++reg) {
            Ll[w][quad * 4 + reg]      = l0[reg];
            Ll[w][quad * 4 + reg + 16] = l1[reg];
        }
    }
    __syncthreads();
    {
        int row = t >> 3, c4 = (t & 7) * 4;
        float4 a = *(const float4*)&Ol[0][row][c4];
        float4 b = *(const float4*)&Ol[1][row][c4];
        float4 d = *(const float4*)&Ol[2][row][c4];
        float4 e = *(const float4*)&Ol[3][row][c4];
        float inv = 1.0f / (Ll[0][row] + Ll[1][row] + Ll[2][row] + Ll[3][row]);
        ushort4 ob;
        ob.x = f2bf((a.x + b.x + d.x + e.x) * inv);
        ob.y = f2bf((a.y + b.y + d.y + e.y) * inv);
        ob.z = f2bf((a.z + b.z + d.z + e.z) * inv);
        ob.w = f2bf((a.w + b.w + d.w + e.w) * inv);
        *(ushort4*)(Ab + (size_t)(r0 + row) * DM + h * HD + c4) = ob;
    }
}

// ---------------------------------------------------------------------------
// Kernel 3: out-projection + bias + residual + LayerNorm, fused.
// Block = 16 rows x 256 cols (4 waves x 64 cols), bf16 weights from prep.
// ---------------------------------------------------------------------------
__global__ __launch_bounds__(256) void proj_ln(
    const unsigned short* __restrict__ Ab, const unsigned short* __restrict__ Wob,
    const float* __restrict__ bo, const float* __restrict__ feat,
    const float* __restrict__ ln_g, const float* __restrict__ ln_b,
    float* __restrict__ out)
{
    __shared__ float red1[4][16], red2[4][16];
    const int t = threadIdx.x, w = t >> 6, lane = t & 63, quad = lane >> 4, c = lane & 15;
    const int r0 = blockIdx.x * 16, c0 = w * 64;

    f32x4 acc[4] = {};
    for (int kt = 0; kt < 8; ++kt) {
        bf16x8 a = *(const bf16x8*)(Ab + (size_t)(r0 + c) * DM + kt * 32 + quad * 8);
#pragma unroll
        for (int ct = 0; ct < 4; ++ct) {
            bf16x8 b = *(const bf16x8*)(Wob + (size_t)(c0 + ct * 16 + c) * DM + kt * 32 + quad * 8);
            acc[ct] = __builtin_amdgcn_mfma_f32_16x16x32_bf16(a, b, acc[ct], 0, 0, 0);
        }
    }
    float y[4][4];
    float s1[4] = {0.f,0.f,0.f,0.f}, s2[4] = {0.f,0.f,0.f,0.f};
#pragma unroll
    for (int ct = 0; ct < 4; ++ct) {
        int col = c0 + ct * 16 + c;
        float bc = bo[col];
#pragma unroll
        for (int reg = 0; reg < 4; ++reg) {
            int r = r0 + quad * 4 + reg;
            float v = acc[ct][reg] + bc + feat[(size_t)r * DM + col];
            y[ct][reg] = v;
            s1[reg] += v; s2[reg] += v * v;
        }
    }
#pragma unroll
    for (int off = 1; off < 16; off <<= 1)
#pragma unroll
        for (int reg = 0; reg < 4; ++reg) {
            s1[reg] += __shfl_xor(s1[reg], off, 16);
            s2[reg] += __shfl_xor(s2[reg], off, 16);
        }
    if (c == 0)
#pragma unroll
        for (int reg = 0; reg < 4; ++reg) {
            red1[w][quad * 4 + reg] = s1[reg];
            red2[w][quad * 4 + reg] = s2[reg];
        }
    __syncthreads();
    float mu[4], rs[4];
#pragma unroll
    for (int reg = 0; reg < 4; ++reg) {
        int row = quad * 4 + reg;
        float a1 = red1[0][row] + red1[1][row] + red1[2][row] + red1[3][row];
        float a2 = red2[0][row] + red2[1][row] + red2[2][row] + red2[3][row];
        float m = a1 * (1.0f / 256.0f);
        mu[reg] = m;
        rs[reg] = rsqrtf(a2 * (1.0f / 256.0f) - m * m + 1e-5f);
    }
#pragma unroll
    for (int ct = 0; ct < 4; ++ct) {
        int col = c0 + ct * 16 + c;
        float g = ln_g[col], bb = ln_b[col];
#pragma unroll
        for (int reg = 0; reg < 4; ++reg) {
            int r = r0 + quad * 4 + reg;
            out[(size_t)r * DM + col] = (y[ct][reg] - mu[reg]) * rs[reg] * g + bb;
        }
    }
}

// ---------------------------------------------------------------------------
extern "C" void kernel_launch(void* const* d_in, const int* in_sizes, int n_in,
                              void* d_out, int out_size, void* d_ws, size_t ws_size,
                              hipStream_t stream) {
    (void)in_sizes; (void)n_in; (void)out_size; (void)ws_size;
    const float* features  = (const float*)d_in[0];
    const float* pointmaps = (const float*)d_in[1];
    const float* Wq = (const float*)d_in[2];  const float* bq = (const float*)d_in[3];
    const float* Wk = (const float*)d_in[4];  const float* bk = (const float*)d_in[5];
    const float* Wv = (const float*)d_in[6];  const float* bv = (const float*)d_in[7];
    const float* Wo = (const float*)d_in[8];  const float* bo = (const float*)d_in[9];
    const float* beta = (const float*)d_in[10];
    const float* k_w1 = (const float*)d_in[11]; const float* k_b1 = (const float*)d_in[12];
    const float* k_w2 = (const float*)d_in[13]; const float* k_b2 = (const float*)d_in[14];
    const float* ln_g = (const float*)d_in[15]; const float* ln_b = (const float*)d_in[16];
    float* out = (float*)d_out;

    char* W = (char*)d_ws;
    unsigned short* xb    = (unsigned short*)(W);             // 1 MB
    unsigned short* Wqb   = (unsigned short*)(W + 1048576);   // 128 KB
    unsigned short* Wkb   = (unsigned short*)(W + 1179648);
    unsigned short* Wvb   = (unsigned short*)(W + 1310720);
    unsigned short* Wob   = (unsigned short*)(W + 1441792);
    float*          T     = (float*)        (W + 1572864);    // 16 KB
    unsigned short* Qb    = (unsigned short*)(W + 1589248);   // 1 MB
    unsigned short* Kb    = (unsigned short*)(W + 2637824);
    unsigned short* Vt    = (unsigned short*)(W + 3686400);
    unsigned short* Ab    = (unsigned short*)(W + 4734976);
    unsigned short* biasP = (unsigned short*)(W + 5783552);   // 8 MB, ends 14.2 MB

    prep       <<<400, 256, 0, stream>>>(features, Wq, Wk, Wv, Wo,
                                         k_w1, k_b1, k_w2, k_b2, beta,
                                         xb, Wqb, Wkb, Wvb, Wob, T);
    fused_front<<<2432, 256, 0, stream>>>(xb, pointmaps,
                                          Wqb, bq, Wkb, bk, Wvb, bv, T,
                                          Qb, Kb, Vt, biasP);
    attn_mfma  <<<dim3(64, 8), 256, 0, stream>>>(Qb, Kb, Vt, biasP, Ab);
    proj_ln    <<<128,         256, 0, stream>>>(Ab, Wob, bo, features, ln_g, ln_b, out);
}

// Round 5
// 136.759 us; speedup vs baseline: 1.0219x; 1.0219x over previous
//
#include <hip/hip_runtime.h>
#include <math.h>

#define L_SEQ 2048
#define DM    256
#define NH    8
#define HD    32

typedef __attribute__((ext_vector_type(8))) short bf16x8;
typedef __attribute__((ext_vector_type(4))) float f32x4;

__device__ __forceinline__ unsigned short f2bf(float f) {
    unsigned int u = __builtin_bit_cast(unsigned int, f);
    u += 0x7fff + ((u >> 16) & 1);          // RNE (finite values only)
    return (unsigned short)(u >> 16);
}

// ---------------------------------------------------------------------------
// Kernel 0: prep.
//  blocks [0,384):  fp32 -> bf16 cvt of x, Wq, Wk, Wv, Wo (8 elems/thread)
//  blocks [384,400): bias-MLP lookup table T[4096] over dist in [0,16]
//                    T[n] = beta * clamp(mlp(n/256), -10, 0), fp32.
// ---------------------------------------------------------------------------
__global__ __launch_bounds__(256) void prep(
    const float* __restrict__ x,  const float* __restrict__ wq,
    const float* __restrict__ wk, const float* __restrict__ wv,
    const float* __restrict__ wo,
    const float* __restrict__ k_w1, const float* __restrict__ k_b1,
    const float* __restrict__ k_w2, const float* __restrict__ k_b2,
    const float* __restrict__ beta_p,
    unsigned short* __restrict__ xb,  unsigned short* __restrict__ wqb,
    unsigned short* __restrict__ wkb, unsigned short* __restrict__ wvb,
    unsigned short* __restrict__ wob, float* __restrict__ T)
{
    const int bx = blockIdx.x, t = threadIdx.x;
    if (bx < 384) {
        int e = (bx * 256 + t) * 8;   // 786432 total elems
        const float* src; unsigned short* dst; int off;
        if      (e < 524288) { src = x;  dst = xb;  off = e; }
        else if (e < 589824) { src = wq; dst = wqb; off = e - 524288; }
        else if (e < 655360) { src = wk; dst = wkb; off = e - 589824; }
        else if (e < 720896) { src = wv; dst = wvb; off = e - 655360; }
        else                 { src = wo; dst = wob; off = e - 720896; }
        float4 u = *(const float4*)(src + off);
        float4 v = *(const float4*)(src + off + 4);
        ushort4 a, b;
        a.x = f2bf(u.x); a.y = f2bf(u.y); a.z = f2bf(u.z); a.w = f2bf(u.w);
        b.x = f2bf(v.x); b.y = f2bf(v.y); b.z = f2bf(v.z); b.w = f2bf(v.w);
        *(ushort4*)(dst + off)     = a;
        *(ushort4*)(dst + off + 4) = b;
    } else {
        int n = (bx - 384) * 256 + t;            // 0..4095
        float d = (float)n * (1.0f / 256.0f);
        float s = 0.f;
#pragma unroll
        for (int k = 0; k < 32; ++k)
            s += fmaxf(fmaf(d, k_w1[k], k_b1[k]), 0.f) * k_w2[k];
        s = fminf(fmaxf(s + k_b2[0], -10.f), 0.f);
        T[n] = beta_p[0] * s;
    }
}

// ---------------------------------------------------------------------------
// Kernel 1: fused front end.
//   blocks [0,384):  QKV projection via MFMA on bf16 inputs.
//                    z = bx>>7 selects Q/K/V; V written TRANSPOSED (Vt[d][key'])
//                    with the permuted key layout (pos = 2*(loc&15)+(loc>>4)).
//   blocks [384,4480): geometric bias via table lerp -> biasP bf16,
//                    same key permutation.
// ---------------------------------------------------------------------------
__global__ __launch_bounds__(256) void fused_front(
    const unsigned short* __restrict__ xb, const float* __restrict__ pts,
    const unsigned short* __restrict__ wqb, const float* __restrict__ bq,
    const unsigned short* __restrict__ wkb, const float* __restrict__ bk,
    const unsigned short* __restrict__ wvb, const float* __restrict__ bv,
    const float* __restrict__ T,
    unsigned short* __restrict__ Qb, unsigned short* __restrict__ Kb,
    unsigned short* __restrict__ Vt, unsigned short* __restrict__ biasP)
{
    const int bx = blockIdx.x;
    const int t = threadIdx.x;

    if (bx < 384) {
        const int z  = bx >> 7;
        const int r0 = (bx & 127) << 4;
        const int w = t >> 6, lane = t & 63, quad = lane >> 4, c = lane & 15;
        const int c0 = w * 64;
        const unsigned short* Wm = (z == 0) ? wqb : (z == 1) ? wkb : wvb;
        const float* bia         = (z == 0) ? bq  : (z == 1) ? bk  : bv;

        f32x4 acc[4] = {};
        for (int kt = 0; kt < 8; ++kt) {
            bf16x8 a = *(const bf16x8*)(xb + (size_t)(r0 + c) * DM + kt * 32 + quad * 8);
#pragma unroll
            for (int ct = 0; ct < 4; ++ct) {
                bf16x8 b = *(const bf16x8*)(Wm + (size_t)(c0 + ct * 16 + c) * DM + kt * 32 + quad * 8);
                acc[ct] = __builtin_amdgcn_mfma_f32_16x16x32_bf16(a, b, acc[ct], 0, 0, 0);
            }
        }
        if (z < 2) {
            unsigned short* out = (z == 0) ? Qb : Kb;
#pragma unroll
            for (int ct = 0; ct < 4; ++ct) {
                float bc = bia[c0 + ct * 16 + c];
#pragma unroll
                for (int reg = 0; reg < 4; ++reg) {
                    int r = r0 + quad * 4 + reg;
                    out[(size_t)r * DM + c0 + ct * 16 + c] = f2bf(acc[ct][reg] + bc);
                }
            }
        } else {
            // V: write transposed with key permutation. Vt[col][pos], col = h*32+d.
#pragma unroll
            for (int ct = 0; ct < 4; ++ct) {
                int col = c0 + ct * 16 + c;
                float bc = bia[col];
#pragma unroll
                for (int reg = 0; reg < 4; ++reg) {
                    int key = r0 + quad * 4 + reg;
                    int loc = key & 31;
                    int pos = (key & ~31) + 2 * (loc & 15) + (loc >> 4);
                    Vt[(size_t)col * L_SEQ + pos] = f2bf(acc[ct][reg] + bc);
                }
            }
        }
    } else {
        const int b = bx - 384;
        const int i = b >> 1;
        const int p0 = ((b & 1) * 256 + t) * 4;
        const float xi = pts[i * 3], yi = pts[i * 3 + 1], zi = pts[i * 3 + 2];

        ushort4 o; unsigned short* po = (unsigned short*)&o;
#pragma unroll
        for (int v = 0; v < 4; ++v) {
            int p = p0 + v, loc = p & 31, base = p & ~31;
            int k = base + (loc >> 1) + 16 * (loc & 1);
            float dx = xi - pts[k * 3], dy = yi - pts[k * 3 + 1], dz = zi - pts[k * 3 + 2];
            float dist = sqrtf(dx * dx + dy * dy + dz * dz);
            float fn = dist * 256.0f;
            int n = (int)fn; n = (n > 4094) ? 4094 : n;
            float fr = fn - (float)n;
            float t0 = T[n], t1 = T[n + 1];
            po[v] = f2bf(fmaf(fr, t1 - t0, t0));
        }
        *(ushort4*)(biasP + (size_t)i * L_SEQ + p0) = o;
    }
}

// ---------------------------------------------------------------------------
// Kernel 2: MFMA flash attention. Block = (32 q-rows, 1 head), 4 waves with
// 4-way key split (512 keys each). Fixed-shift softmax (M=10) -> partials
// combine by plain sums. No __syncthreads in the K-loop; P does a wave-local
// LDS transpose (C-layout -> A-layout) in the permuted key order.
// ---------------------------------------------------------------------------
__global__ __launch_bounds__(256) void attn_mfma(
    const unsigned short* __restrict__ Qb, const unsigned short* __restrict__ Kb,
    const unsigned short* __restrict__ Vt, const unsigned short* __restrict__ biasP,
    unsigned short* __restrict__ Ab)
{
    __shared__ unsigned short Plds[4][32][40];
    __shared__ float Ol[4][32][36];
    __shared__ float Ll[4][32];
    const int t = threadIdx.x, w = t >> 6, lane = t & 63, quad = lane >> 4, c = lane & 15;
    const int h = blockIdx.y, r0 = blockIdx.x * 32;
    const int kbase = w * 512;
    const f32x4 Z = {};

    bf16x8 qf0 = *(const bf16x8*)(Qb + (size_t)(r0 + c) * DM + h * HD + quad * 8);
    bf16x8 qf1 = *(const bf16x8*)(Qb + (size_t)(r0 + 16 + c) * DM + h * HD + quad * 8);

    f32x4 O00 = {}, O01 = {}, O10 = {}, O11 = {};
    float l0[4] = {0.f,0.f,0.f,0.f}, l1[4] = {0.f,0.f,0.f,0.f};

    const float LOG2E = 1.4426950408889634f;
    const float C1 = 0.17677669529663687f * LOG2E;  // SCALE * log2e
    const float MC = -10.0f * LOG2E;                // fixed shift

    const unsigned short* Kp  = Kb + (size_t)h * HD + quad * 8;
    const unsigned short* Vp0 = Vt + (size_t)(h * HD + c) * L_SEQ + quad * 8;
    const unsigned short* Vp1 = Vt + (size_t)(h * HD + 16 + c) * L_SEQ + quad * 8;
    const int br0 = r0 + quad * 4;

    bf16x8 kf0 = *(const bf16x8*)(Kp + (size_t)(kbase + c) * DM);
    bf16x8 kf1 = *(const bf16x8*)(Kp + (size_t)(kbase + 16 + c) * DM);
    bf16x8 vf0 = *(const bf16x8*)(Vp0 + kbase);
    bf16x8 vf1 = *(const bf16x8*)(Vp1 + kbase);
    unsigned int bu0[4], bu1[4];
#pragma unroll
    for (int reg = 0; reg < 4; ++reg) {
        bu0[reg] = *(const unsigned int*)(biasP + (size_t)(br0 + reg) * L_SEQ + kbase + c * 2);
        bu1[reg] = *(const unsigned int*)(biasP + (size_t)(br0 + 16 + reg) * L_SEQ + kbase + c * 2);
    }

    for (int kt = 0; kt < 16; ++kt) {
        const int kn = kbase + (kt + 1) * 32;
        bf16x8 nk0 = kf0, nk1 = kf1, nv0 = vf0, nv1 = vf1;
        unsigned int nbu0[4], nbu1[4];
#pragma unroll
        for (int reg = 0; reg < 4; ++reg) { nbu0[reg] = bu0[reg]; nbu1[reg] = bu1[reg]; }
        if (kt < 15) {   // prefetch next tile's fragments (no barrier in this loop)
            nk0 = *(const bf16x8*)(Kp + (size_t)(kn + c) * DM);
            nk1 = *(const bf16x8*)(Kp + (size_t)(kn + 16 + c) * DM);
            nv0 = *(const bf16x8*)(Vp0 + kn);
            nv1 = *(const bf16x8*)(Vp1 + kn);
#pragma unroll
            for (int reg = 0; reg < 4; ++reg) {
                nbu0[reg] = *(const unsigned int*)(biasP + (size_t)(br0 + reg) * L_SEQ + kn + c * 2);
                nbu1[reg] = *(const unsigned int*)(biasP + (size_t)(br0 + 16 + reg) * L_SEQ + kn + c * 2);
            }
        }

        f32x4 S00 = __builtin_amdgcn_mfma_f32_16x16x32_bf16(qf0, kf0, Z, 0, 0, 0);
        f32x4 S01 = __builtin_amdgcn_mfma_f32_16x16x32_bf16(qf0, kf1, Z, 0, 0, 0);
        f32x4 S10 = __builtin_amdgcn_mfma_f32_16x16x32_bf16(qf1, kf0, Z, 0, 0, 0);
        f32x4 S11 = __builtin_amdgcn_mfma_f32_16x16x32_bf16(qf1, kf1, Z, 0, 0, 0);

#pragma unroll
        for (int reg = 0; reg < 4; ++reg) {
            unsigned int u = bu0[reg];
            float blo = __builtin_bit_cast(float, u << 16);
            float bhi = __builtin_bit_cast(float, u & 0xffff0000u);
            float p0 = __builtin_exp2f(fmaf(S00[reg], C1, fmaf(blo, LOG2E, MC)));
            float p1 = __builtin_exp2f(fmaf(S01[reg], C1, fmaf(bhi, LOG2E, MC)));
            l0[reg] += p0 + p1;
            unsigned int pb = __builtin_amdgcn_perm(
                __builtin_bit_cast(unsigned int, p1),
                __builtin_bit_cast(unsigned int, p0), 0x07060302);
            *(unsigned int*)&Plds[w][quad * 4 + reg][c * 2] = pb;

            u = bu1[reg];
            blo = __builtin_bit_cast(float, u << 16);
            bhi = __builtin_bit_cast(float, u & 0xffff0000u);
            p0 = __builtin_exp2f(fmaf(S10[reg], C1, fmaf(blo, LOG2E, MC)));
            p1 = __builtin_exp2f(fmaf(S11[reg], C1, fmaf(bhi, LOG2E, MC)));
            l1[reg] += p0 + p1;
            pb = __builtin_amdgcn_perm(
                __builtin_bit_cast(unsigned int, p1),
                __builtin_bit_cast(unsigned int, p0), 0x07060302);
            *(unsigned int*)&Plds[w][16 + quad * 4 + reg][c * 2] = pb;
        }

        bf16x8 pa0 = *(const bf16x8*)&Plds[w][c][quad * 8];
        bf16x8 pa1 = *(const bf16x8*)&Plds[w][16 + c][quad * 8];
        O00 = __builtin_amdgcn_mfma_f32_16x16x32_bf16(pa0, vf0, O00, 0, 0, 0);
        O01 = __builtin_amdgcn_mfma_f32_16x16x32_bf16(pa0, vf1, O01, 0, 0, 0);
        O10 = __builtin_amdgcn_mfma_f32_16x16x32_bf16(pa1, vf0, O10, 0, 0, 0);
        O11 = __builtin_amdgcn_mfma_f32_16x16x32_bf16(pa1, vf1, O11, 0, 0, 0);

        kf0 = nk0; kf1 = nk1; vf0 = nv0; vf1 = nv1;
#pragma unroll
        for (int reg = 0; reg < 4; ++reg) { bu0[reg] = nbu0[reg]; bu1[reg] = nbu1[reg]; }
    }

    // reduce l across the 16 lanes of each quad (rows live per (quad,reg))
#pragma unroll
    for (int off = 1; off < 16; off <<= 1) {
#pragma unroll
        for (int reg = 0; reg < 4; ++reg) {
            l0[reg] += __shfl_xor(l0[reg], off, 16);
            l1[reg] += __shfl_xor(l1[reg], off, 16);
        }
    }
    // dump per-wave partials (plain sums thanks to fixed shift)
#pragma unroll
    for (int reg = 0; reg < 4; ++reg) {
        int row = quad * 4 + reg;
        Ol[w][row][c]           = O00[reg];
        Ol[w][row][16 + c]      = O01[reg];
        Ol[w][row + 16][c]      = O10[reg];
        Ol[w][row + 16][16 + c] = O11[reg];
    }
    if (c == 0) {
#pragma unroll
        for (int reg = 0; reg < 4; ++reg) {
            Ll[w][quad * 4 + reg]      = l0[reg];
            Ll[w][quad * 4 + reg + 16] = l1[reg];
        }
    }
    __syncthreads();
    {
        int row = t >> 3, c4 = (t & 7) * 4;
        float4 a = *(const float4*)&Ol[0][row][c4];
        float4 b = *(const float4*)&Ol[1][row][c4];
        float4 d = *(const float4*)&Ol[2][row][c4];
        float4 e = *(const float4*)&Ol[3][row][c4];
        float inv = 1.0f / (Ll[0][row] + Ll[1][row] + Ll[2][row] + Ll[3][row]);
        ushort4 ob;
        ob.x = f2bf((a.x + b.x + d.x + e.x) * inv);
        ob.y = f2bf((a.y + b.y + d.y + e.y) * inv);
        ob.z = f2bf((a.z + b.z + d.z + e.z) * inv);
        ob.w = f2bf((a.w + b.w + d.w + e.w) * inv);
        *(ushort4*)(Ab + (size_t)(r0 + row) * DM + h * HD + c4) = ob;
    }
}

// ---------------------------------------------------------------------------
// Kernel 3: out-projection + bias + residual + LayerNorm, fused.
// Block = 16 rows x 256 cols (4 waves x 64 cols), bf16 weights from prep.
// ---------------------------------------------------------------------------
__global__ __launch_bounds__(256) void proj_ln(
    const unsigned short* __restrict__ Ab, const unsigned short* __restrict__ Wob,
    const float* __restrict__ bo, const float* __restrict__ feat,
    const float* __restrict__ ln_g, const float* __restrict__ ln_b,
    float* __restrict__ out)
{
    __shared__ float red1[4][16], red2[4][16];
    const int t = threadIdx.x, w = t >> 6, lane = t & 63, quad = lane >> 4, c = lane & 15;
    const int r0 = blockIdx.x * 16, c0 = w * 64;

    f32x4 acc[4] = {};
    for (int kt = 0; kt < 8; ++kt) {
        bf16x8 a = *(const bf16x8*)(Ab + (size_t)(r0 + c) * DM + kt * 32 + quad * 8);
#pragma unroll
        for (int ct = 0; ct < 4; ++ct) {
            bf16x8 b = *(const bf16x8*)(Wob + (size_t)(c0 + ct * 16 + c) * DM + kt * 32 + quad * 8);
            acc[ct] = __builtin_amdgcn_mfma_f32_16x16x32_bf16(a, b, acc[ct], 0, 0, 0);
        }
    }
    float y[4][4];
    float s1[4] = {0.f,0.f,0.f,0.f}, s2[4] = {0.f,0.f,0.f,0.f};
#pragma unroll
    for (int ct = 0; ct < 4; ++ct) {
        int col = c0 + ct * 16 + c;
        float bc = bo[col];
#pragma unroll
        for (int reg = 0; reg < 4; ++reg) {
            int r = r0 + quad * 4 + reg;
            float v = acc[ct][reg] + bc + feat[(size_t)r * DM + col];
            y[ct][reg] = v;
            s1[reg] += v; s2[reg] += v * v;
        }
    }
#pragma unroll
    for (int off = 1; off < 16; off <<= 1)
#pragma unroll
        for (int reg = 0; reg < 4; ++reg) {
            s1[reg] += __shfl_xor(s1[reg], off, 16);
            s2[reg] += __shfl_xor(s2[reg], off, 16);
        }
    if (c == 0)
#pragma unroll
        for (int reg = 0; reg < 4; ++reg) {
            red1[w][quad * 4 + reg] = s1[reg];
            red2[w][quad * 4 + reg] = s2[reg];
        }
    __syncthreads();
    float mu[4], rs[4];
#pragma unroll
    for (int reg = 0; reg < 4; ++reg) {
        int row = quad * 4 + reg;
        float a1 = red1[0][row] + red1[1][row] + red1[2][row] + red1[3][row];
        float a2 = red2[0][row] + red2[1][row] + red2[2][row] + red2[3][row];
        float m = a1 * (1.0f / 256.0f);
        mu[reg] = m;
        rs[reg] = rsqrtf(a2 * (1.0f / 256.0f) - m * m + 1e-5f);
    }
#pragma unroll
    for (int ct = 0; ct < 4; ++ct) {
        int col = c0 + ct * 16 + c;
        float g = ln_g[col], bb = ln_b[col];
#pragma unroll
        for (int reg = 0; reg < 4; ++reg) {
            int r = r0 + quad * 4 + reg;
            out[(size_t)r * DM + col] = (y[ct][reg] - mu[reg]) * rs[reg] * g + bb;
        }
    }
}

// ---------------------------------------------------------------------------
extern "C" void kernel_launch(void* const* d_in, const int* in_sizes, int n_in,
                              void* d_out, int out_size, void* d_ws, size_t ws_size,
                              hipStream_t stream) {
    (void)in_sizes; (void)n_in; (void)out_size; (void)ws_size;
    const float* features  = (const float*)d_in[0];
    const float* pointmaps = (const float*)d_in[1];
    const float* Wq = (const float*)d_in[2];  const float* bq = (const float*)d_in[3];
    const float* Wk = (const float*)d_in[4];  const float* bk = (const float*)d_in[5];
    const float* Wv = (const float*)d_in[6];  const float* bv = (const float*)d_in[7];
    const float* Wo = (const float*)d_in[8];  const float* bo = (const float*)d_in[9];
    const float* beta = (const float*)d_in[10];
    const float* k_w1 = (const float*)d_in[11]; const float* k_b1 = (const float*)d_in[12];
    const float* k_w2 = (const float*)d_in[13]; const float* k_b2 = (const float*)d_in[14];
    const float* ln_g = (const float*)d_in[15]; const float* ln_b = (const float*)d_in[16];
    float* out = (float*)d_out;

    char* W = (char*)d_ws;
    unsigned short* xb    = (unsigned short*)(W);             // 1 MB
    unsigned short* Wqb   = (unsigned short*)(W + 1048576);   // 128 KB
    unsigned short* Wkb   = (unsigned short*)(W + 1179648);
    unsigned short* Wvb   = (unsigned short*)(W + 1310720);
    unsigned short* Wob   = (unsigned short*)(W + 1441792);
    float*          T     = (float*)        (W + 1572864);    // 16 KB
    unsigned short* Qb    = (unsigned short*)(W + 1589248);   // 1 MB
    unsigned short* Kb    = (unsigned short*)(W + 2637824);
    unsigned short* Vt    = (unsigned short*)(W + 3686400);
    unsigned short* Ab    = (unsigned short*)(W + 4734976);
    unsigned short* biasP = (unsigned short*)(W + 5783552);   // 8 MB, ends 14.2 MB

    prep       <<<400, 256, 0, stream>>>(features, Wq, Wk, Wv, Wo,
                                         k_w1, k_b1, k_w2, k_b2, beta,
                                         xb, Wqb, Wkb, Wvb, Wob, T);
    fused_front<<<4480, 256, 0, stream>>>(xb, pointmaps,
                                          Wqb, bq, Wkb, bk, Wvb, bv, T,
                                          Qb, Kb, Vt, biasP);
    attn_mfma  <<<dim3(64, 8), 256, 0, stream>>>(Qb, Kb, Vt, biasP, Ab);
    proj_ln    <<<128,         256, 0, stream>>>(Ab, Wob, bo, features, ln_g, ln_b, out);
}